// Round 1
// baseline (11967.584 us; speedup 1.0000x reference)
//
#include <hip/hip_runtime.h>
#include <cstddef>
#include <cstdint>

// ---------------------------------------------------------------------------
// GridNetBlock forward, fp32. Shapes: B=2,T=512,QF=64,C=128,H=256,KD=4,NH=4,
// E=8,VD=32,L=100.  N=B*T=1024, rows_inter=B*QF=128, S=T+L-1=611.
// Workspace requirement: 35,897,344 floats = 143,589,376 bytes (~137 MiB).
// ---------------------------------------------------------------------------

#define EPSV 1e-5f

// ---- workspace offsets (in floats) ----
#define O_WCT   0            // 65536  : W_conv transposed [k*128+c][o]
#define O_BDE   65536        // 512    : b_deconv expanded to cols o*4+k
#define O_WILT  66048        // 32768  : W_il^T [h][c]
#define O_WQK   98816        // 8192   : [c][ he<32:Wq, else Wk ]
#define O_WVT   107008       // 16384  : Wv^T [c][o]
#define O_WPT   123392       // 16384  : Wp^T [c][o]
#define O_HF0   262144       // intra fwd h ping (1024x256)
#define O_HF1   524288
#define O_CF    786432
#define O_HB0   1048576
#define O_HB1   1310720
#define O_CB    1572864
#define O_HI0   1835008      // inter h ping (128x256)
#define O_HI1   1867776
#define O_CI    1900544
#define O_ATTN  1933312      // 8*512*100 = 409600
#define O_R1    2342912      // 16,777,216 floats
#define O_R2    19120128     // 8,388,608
#define O_R3    27508736     // 8,388,608
// total end: 35,897,344 floats

static __device__ __forceinline__ float sigm(float x) { return 1.f / (1.f + __expf(-x)); }
static __device__ __forceinline__ float tanhfast(float x) { return 1.f - 2.f / (__expf(2.f * x) + 1.f); }

// ---------------------------------------------------------------------------
// one-time weight reshuffles
// ---------------------------------------------------------------------------
__global__ __launch_bounds__(256) void prep_weights(
    const float* __restrict__ Wc, const float* __restrict__ bdec,
    const float* __restrict__ Wil, const float* __restrict__ Wq,
    const float* __restrict__ Wk, const float* __restrict__ Wv,
    const float* __restrict__ Wp, float* __restrict__ ws)
{
  int idx = blockIdx.x * 256 + threadIdx.x;
  if (idx < 65536) { // WcT[i=k*128+c][o] = W_conv[o][c][k]
    int i = idx >> 7, o = idx & 127;
    ws[O_WCT + idx] = Wc[o * 512 + (i & 127) * 4 + (i >> 7)];
    return;
  }
  idx -= 65536;
  if (idx < 512) { ws[O_BDE + idx] = bdec[idx >> 2]; return; }
  idx -= 512;
  if (idx < 32768) { // WilT[h][c] = W_il[c][h]
    int h = idx >> 7, c = idx & 127;
    ws[O_WILT + idx] = Wil[c * 256 + h];
    return;
  }
  idx -= 32768;
  if (idx < 8192) { // Wqk[c][he]
    int c = idx >> 6, he = idx & 63;
    ws[O_WQK + idx] = (he < 32) ? Wq[he * 128 + c] : Wk[(he - 32) * 128 + c];
    return;
  }
  idx -= 8192;
  if (idx < 16384) { int c = idx >> 7, o = idx & 127; ws[O_WVT + idx] = Wv[o * 128 + c]; return; }
  idx -= 16384;
  if (idx < 16384) { int c = idx >> 7, o = idx & 127; ws[O_WPT + idx] = Wp[o * 128 + c]; return; }
}

// ---------------------------------------------------------------------------
// generic fp32 GEMM: C[M][N] = A[M][K] * B[K][N] (+bias[N]) (+prelu(a))
// M%64==0, N%64==0, K%16==0.  64x64 tile, 256 threads, 4x4 per thread.
// ---------------------------------------------------------------------------
__global__ __launch_bounds__(256) void gemm64(
    const float* __restrict__ A, const float* __restrict__ B, float* __restrict__ C,
    int M, int N, int K, const float* __restrict__ bias, const float* __restrict__ pa)
{
  __shared__ float As[16][68]; // As[k][m]
  __shared__ float Bs[16][68]; // Bs[k][n]
  const int bm = blockIdx.x * 64, bn = blockIdx.y * 64;
  const int tid = threadIdx.x;
  const int tr = tid & 15;   // col group
  const int tc = tid >> 4;   // row group
  float acc[4][4] = {};
  for (int k0 = 0; k0 < K; k0 += 16) {
    int i = tid;
#pragma unroll
    for (int it = 0; it < 4; ++it, i += 256) {
      int mi = i >> 4, ki = i & 15;
      As[ki][mi] = A[(size_t)(bm + mi) * K + k0 + ki];
    }
    i = tid;
#pragma unroll
    for (int it = 0; it < 4; ++it, i += 256) {
      int ki = i >> 6, ni = i & 63;
      Bs[ki][ni] = B[(size_t)(k0 + ki) * N + bn + ni];
    }
    __syncthreads();
#pragma unroll
    for (int kk = 0; kk < 16; ++kk) {
      float4 a = *(const float4*)&As[kk][tc * 4];
      float4 b = *(const float4*)&Bs[kk][tr * 4];
      acc[0][0] += a.x * b.x; acc[0][1] += a.x * b.y; acc[0][2] += a.x * b.z; acc[0][3] += a.x * b.w;
      acc[1][0] += a.y * b.x; acc[1][1] += a.y * b.y; acc[1][2] += a.y * b.z; acc[1][3] += a.y * b.w;
      acc[2][0] += a.z * b.x; acc[2][1] += a.z * b.y; acc[2][2] += a.z * b.z; acc[2][3] += a.z * b.w;
      acc[3][0] += a.w * b.x; acc[3][1] += a.w * b.y; acc[3][2] += a.w * b.z; acc[3][3] += a.w * b.w;
    }
    __syncthreads();
  }
  const float aval = pa ? pa[0] : 0.f;
#pragma unroll
  for (int ii = 0; ii < 4; ++ii) {
    int m = bm + tc * 4 + ii;
#pragma unroll
    for (int jj = 0; jj < 4; ++jj) {
      int n = bn + tr * 4 + jj;
      float v = acc[ii][jj];
      if (bias) v += bias[n];
      if (pa) v = v >= 0.f ? v : aval * v;
      C[(size_t)m * N + n] = v;
    }
  }
}

// ---------------------------------------------------------------------------
// generic LayerNorm over last dim D of in[rows][D]; optional row permutation of
// the OUTPUT (mode 1: (b,t,qf) -> (b,qf,t) for the inter-LSTM input), optional
// residual add (addsrc, indexed like out).  in==out allowed.
// ---------------------------------------------------------------------------
__global__ __launch_bounds__(256) void ln_rows(
    const float* in, float* out, int D,
    const float* __restrict__ g, const float* __restrict__ b,
    const float* addsrc, int permmode)
{
  const int row = blockIdx.x;
  size_t orow = row;
  if (permmode == 1) {
    int bb = row >> 15, t = (row >> 6) & 511, qf = row & 63;
    orow = (size_t)((bb << 6) | qf) * 512 + t;
  }
  const float* p = in + (size_t)row * D;
  float s = 0.f, s2 = 0.f;
  for (int i = threadIdx.x; i < D; i += 256) { float v = p[i]; s += v; s2 += v * v; }
#pragma unroll
  for (int m = 1; m < 64; m <<= 1) { s += __shfl_xor(s, m); s2 += __shfl_xor(s2, m); }
  __shared__ float red[2][4];
  const int w = threadIdx.x >> 6;
  if ((threadIdx.x & 63) == 0) { red[0][w] = s; red[1][w] = s2; }
  __syncthreads();
  s  = red[0][0] + red[0][1] + red[0][2] + red[0][3];
  s2 = red[1][0] + red[1][1] + red[1][2] + red[1][3];
  const float invD = 1.f / (float)D;
  const float mean = s * invD;
  const float var  = s2 * invD - mean * mean;
  const float rstd = rsqrtf(var + EPSV);
  float* q = out + orow * D;
  const float* asrc = addsrc ? addsrc + orow * D : nullptr;
  for (int i = threadIdx.x; i < D; i += 256) {
    float v = (p[i] - mean) * rstd * g[i] + b[i];
    if (asrc) v += asrc[i];
    q[i] = v;
  }
}

// ---------------------------------------------------------------------------
// one LSTM time step (gates fused: x@Wih^T + h@Whh^T + bih + bhh), torch gate
// order i,f,g,o.  grid = (rows/16, 16), block 256: thread (r=tid&15, kk=tid>>4)
// computes the 4 gates of hidden unit kh = by*16+kk for row r of its 16-row
// block. h ping-pong; c in-place; h also written to y_out sequence buffer.
// ---------------------------------------------------------------------------
__global__ __launch_bounds__(256) void lstm_step(
    const float* __restrict__ xseq, int t_x, int TT,
    const float* __restrict__ Wih, const float* __restrict__ Whh,
    const float* __restrict__ bih, const float* __restrict__ bhh,
    const float* __restrict__ h_prev, float* __restrict__ h_next,
    float* __restrict__ c_state,
    float* __restrict__ y_out, int y_TT, int y_stride, int y_off, int t_y)
{
  __shared__ float xs[16][132];
  __shared__ float hs[16][260];
  const int tid = threadIdx.x;
  const int r = tid & 15, kk = tid >> 4;
  const int row0 = blockIdx.x * 16;
  const int kh = blockIdx.y * 16 + kk;
  for (int i = tid; i < 16 * 128; i += 256) {
    int rr = i >> 7, cc = i & 127;
    xs[rr][cc] = xseq[((size_t)(row0 + rr) * TT + t_x) * 128 + cc];
  }
  for (int i = tid; i < 16 * 256; i += 256) {
    int rr = i >> 8, cc = i & 255;
    hs[rr][cc] = h_prev[(size_t)(row0 + rr) * 256 + cc];
  }
  __syncthreads();
  float acc0 = bih[kh]       + bhh[kh];
  float acc1 = bih[kh + 256] + bhh[kh + 256];
  float acc2 = bih[kh + 512] + bhh[kh + 512];
  float acc3 = bih[kh + 768] + bhh[kh + 768];
  const float4* Wi0 = (const float4*)(Wih + (size_t)kh * 128);
  const float4* Wi1 = (const float4*)(Wih + (size_t)(kh + 256) * 128);
  const float4* Wi2 = (const float4*)(Wih + (size_t)(kh + 512) * 128);
  const float4* Wi3 = (const float4*)(Wih + (size_t)(kh + 768) * 128);
#pragma unroll 8
  for (int c4 = 0; c4 < 32; ++c4) {
    float4 xv = *(const float4*)&xs[r][c4 * 4];
    float4 w0 = Wi0[c4], w1 = Wi1[c4], w2 = Wi2[c4], w3 = Wi3[c4];
    acc0 += xv.x * w0.x + xv.y * w0.y + xv.z * w0.z + xv.w * w0.w;
    acc1 += xv.x * w1.x + xv.y * w1.y + xv.z * w1.z + xv.w * w1.w;
    acc2 += xv.x * w2.x + xv.y * w2.y + xv.z * w2.z + xv.w * w2.w;
    acc3 += xv.x * w3.x + xv.y * w3.y + xv.z * w3.z + xv.w * w3.w;
  }
  const float4* Wh0 = (const float4*)(Whh + (size_t)kh * 256);
  const float4* Wh1 = (const float4*)(Whh + (size_t)(kh + 256) * 256);
  const float4* Wh2 = (const float4*)(Whh + (size_t)(kh + 512) * 256);
  const float4* Wh3 = (const float4*)(Whh + (size_t)(kh + 768) * 256);
#pragma unroll 8
  for (int k4 = 0; k4 < 64; ++k4) {
    float4 hv = *(const float4*)&hs[r][k4 * 4];
    float4 w0 = Wh0[k4], w1 = Wh1[k4], w2 = Wh2[k4], w3 = Wh3[k4];
    acc0 += hv.x * w0.x + hv.y * w0.y + hv.z * w0.z + hv.w * w0.w;
    acc1 += hv.x * w1.x + hv.y * w1.y + hv.z * w1.z + hv.w * w1.w;
    acc2 += hv.x * w2.x + hv.y * w2.y + hv.z * w2.z + hv.w * w2.w;
    acc3 += hv.x * w3.x + hv.y * w3.y + hv.z * w3.z + hv.w * w3.w;
  }
  const int row = row0 + r;
  const float ig = sigm(acc0), fg = sigm(acc1);
  const float gg = tanhfast(acc2), og = sigm(acc3);
  const size_t ci = (size_t)row * 256 + kh;
  const float cn = fg * c_state[ci] + ig * gg;
  c_state[ci] = cn;
  const float hv = og * tanhfast(cn);
  h_next[ci] = hv;
  y_out[((size_t)row * y_TT + t_y) * y_stride + y_off + kh] = hv;
}

// ---------------------------------------------------------------------------
// permute/epilogue kernels
// ---------------------------------------------------------------------------
__global__ __launch_bounds__(256) void perm_dec_add(
    const float* __restrict__ Cd, const float* __restrict__ x, float* __restrict__ x1)
{
  int idx = blockIdx.x * 256 + threadIdx.x; // 8,388,608
  int n = idx >> 13, f = (idx >> 7) & 63, o = idx & 127;
  x1[idx] = Cd[(size_t)(n * 16 + (f >> 2)) * 512 + (o << 2) + (f & 3)] + x[idx];
}

__global__ __launch_bounds__(256) void perm_wil_add(
    const float* __restrict__ C3, const float* __restrict__ x1, float* __restrict__ dout)
{
  int idx = blockIdx.x * 256 + threadIdx.x; // 8,388,608
  int rid = idx >> 7, c = idx & 127;
  int bb = rid >> 15, t = (rid >> 6) & 511, qf = rid & 63;
  dout[idx] = C3[(size_t)(((bb << 6) | qf) * 512 + t) * 128 + c] + x1[idx];
}

__global__ __launch_bounds__(256) void scat_qk(
    const float* __restrict__ C4, const float* __restrict__ bq, const float* __restrict__ bk,
    const float* __restrict__ aq, const float* __restrict__ ak,
    float* __restrict__ Qm, float* __restrict__ Km)
{
  int idx = blockIdx.x * 256 + threadIdx.x; // 4,194,304
  int row = idx >> 6, he = idx & 63;
  int bb = row >> 15, t = (row >> 6) & 511, q = row & 63;
  bool isQ = he < 32;
  int e32 = he & 31;
  float v = C4[idx] + (isQ ? bq[e32] : bk[e32]);
  float a = isQ ? aq[0] : ak[0];
  v = v >= 0.f ? v : a * v;
  float* dst = isQ ? Qm : Km;
  dst[((size_t)(bb * 4 + (e32 >> 3)) * 512 + t) * 512 + q * 8 + (e32 & 7)] = v;
}

__global__ __launch_bounds__(256) void scat_v(
    const float* __restrict__ C5, const float* __restrict__ bv,
    const float* __restrict__ av, float* __restrict__ Vm)
{
  int idx = blockIdx.x * 256 + threadIdx.x; // 8,388,608
  int row = idx >> 7, o = idx & 127;
  int bb = row >> 15, t = (row >> 6) & 511, q = row & 63;
  float v = C5[idx] + bv[o];
  v = v >= 0.f ? v : av[0] * v;
  Vm[((size_t)(bb * 4 + (o >> 5)) * 512 + t) * 2048 + q * 32 + (o & 31)] = v;
}

__global__ __launch_bounds__(256) void gather_y(
    const float* __restrict__ Vo, float* __restrict__ yg)
{
  int idx = blockIdx.x * 256 + threadIdx.x; // 8,388,608
  int rid = idx >> 7, c = idx & 127;
  int bb = rid >> 15, t = (rid >> 6) & 511, q = rid & 63;
  yg[idx] = Vo[((size_t)(bb * 4 + (c >> 5)) * 512 + t) * 2048 + q * 32 + (c & 31)];
}

// ---------------------------------------------------------------------------
// banded attention: scores + softmax.  grid (32 t-blocks, 8 bh), block 256 =
// (q=tid>>4 local query, li=tid&15).  Each query t attends Kf[t : t+100].
// ---------------------------------------------------------------------------
__global__ __launch_bounds__(256) void attn_scores(
    const float* __restrict__ Qm, const float* __restrict__ Km,
    const float* __restrict__ Kbuf, float* __restrict__ attnw)
{
  __shared__ float Qs[16][512];
  __shared__ float sc[16][104];
  const int tb = blockIdx.x, bh = blockIdx.y;
  const int t0 = tb * 16;
  for (int i = threadIdx.x; i < 8192; i += 256) {
    int rr = i >> 9, d = i & 511;
    Qs[rr][d] = Qm[((size_t)(bh * 512) + t0 + rr) * 512 + d];
  }
  __syncthreads();
  const int q = threadIdx.x >> 4, li = threadIdx.x & 15;
  const float isc = 0.044194173824159216f; // 1/sqrt(512)
  for (int chunk = 0; chunk < 8; ++chunk) {
    int off = chunk * 16 + li;
    int sl = off - q;
    if (off <= 114 && sl >= 0 && sl < 100) {
      int sp = t0 + off;
      const float* Kr = (sp < 99) ? (Kbuf + ((size_t)bh * 99 + sp) * 512)
                                  : (Km + ((size_t)bh * 512 + (sp - 99)) * 512);
      const float4* K4 = (const float4*)Kr;
      const float4* Q4 = (const float4*)&Qs[q][0];
      float dot = 0.f;
      for (int d4 = 0; d4 < 128; ++d4) {
        float4 kv = K4[d4], qv = Q4[d4];
        dot += kv.x * qv.x + kv.y * qv.y + kv.z * qv.z + kv.w * qv.w;
      }
      sc[q][sl] = dot * isc;
    }
  }
  __syncthreads();
  float mx = -1e30f;
  for (int s = li; s < 100; s += 16) mx = fmaxf(mx, sc[q][s]);
#pragma unroll
  for (int m = 1; m < 16; m <<= 1) mx = fmaxf(mx, __shfl_xor(mx, m, 16));
  float sum = 0.f;
  for (int s = li; s < 100; s += 16) sum += __expf(sc[q][s] - mx);
#pragma unroll
  for (int m = 1; m < 16; m <<= 1) sum += __shfl_xor(sum, m, 16);
  const float rinv = 1.f / sum;
  for (int s = li; s < 100; s += 16)
    attnw[((size_t)(bh * 512) + t0 + q) * 100 + s] = __expf(sc[q][s] - mx) * rinv;
}

// PV: Vo[bh,t,:] = sum_s attn[t,s] * Vf[t+s,:].  grid (64 q-blocks of 8, 8 bh),
// block 256; each thread owns 8 consecutive d for all 8 queries.
__global__ __launch_bounds__(256) void attn_pv(
    const float* __restrict__ attnw, const float* __restrict__ Vm,
    const float* __restrict__ Vbuf, float* __restrict__ Vo)
{
  __shared__ float atn[8][100];
  const int qb = blockIdx.x, bh = blockIdx.y;
  const int t0 = qb * 8;
  for (int i = threadIdx.x; i < 800; i += 256) {
    int qq = i / 100, sl = i - qq * 100;
    atn[qq][sl] = attnw[((size_t)(bh * 512) + t0 + qq) * 100 + sl];
  }
  __syncthreads();
  float4 a0[8], a1[8];
#pragma unroll
  for (int qq = 0; qq < 8; ++qq) {
    a0[qq] = make_float4(0.f, 0.f, 0.f, 0.f);
    a1[qq] = make_float4(0.f, 0.f, 0.f, 0.f);
  }
  for (int j = 0; j < 107; ++j) {
    int sp = t0 + j;
    const float* Vr = (sp < 99) ? (Vbuf + ((size_t)bh * 99 + sp) * 2048)
                                : (Vm + ((size_t)bh * 512 + (sp - 99)) * 2048);
    float4 v0 = ((const float4*)Vr)[threadIdx.x * 2];
    float4 v1 = ((const float4*)Vr)[threadIdx.x * 2 + 1];
#pragma unroll
    for (int qq = 0; qq < 8; ++qq) {
      int sl = j - qq;
      if (sl >= 0 && sl < 100) {
        float wgt = atn[qq][sl];
        a0[qq].x += wgt * v0.x; a0[qq].y += wgt * v0.y; a0[qq].z += wgt * v0.z; a0[qq].w += wgt * v0.w;
        a1[qq].x += wgt * v1.x; a1[qq].y += wgt * v1.y; a1[qq].z += wgt * v1.z; a1[qq].w += wgt * v1.w;
      }
    }
  }
#pragma unroll
  for (int qq = 0; qq < 8; ++qq) {
    float4* dst = (float4*)(Vo + ((size_t)(bh * 512) + t0 + qq) * 2048);
    dst[threadIdx.x * 2] = a0[qq];
    dst[threadIdx.x * 2 + 1] = a1[qq];
  }
}

// ---------------------------------------------------------------------------
extern "C" void kernel_launch(void* const* d_in, const int* in_sizes, int n_in,
                              void* d_out, int out_size, void* d_ws, size_t ws_size,
                              hipStream_t stream) {
  (void)in_sizes; (void)n_in; (void)out_size; (void)ws_size;
  const float* x      = (const float*)d_in[0];
  const float* Wc     = (const float*)d_in[1];
  const float* bconv  = (const float*)d_in[2];
  const float* a_act  = (const float*)d_in[3];
  const float* gnorm  = (const float*)d_in[4];
  const float* bnorm  = (const float*)d_in[5];
  const float* Wih_f  = (const float*)d_in[6];
  const float* Whh_f  = (const float*)d_in[7];
  const float* bih_f  = (const float*)d_in[8];
  const float* bhh_f  = (const float*)d_in[9];
  const float* Wih_b  = (const float*)d_in[10];
  const float* Whh_b  = (const float*)d_in[11];
  const float* bih_b  = (const float*)d_in[12];
  const float* bhh_b  = (const float*)d_in[13];
  const float* Wih_i  = (const float*)d_in[14];
  const float* Whh_i  = (const float*)d_in[15];
  const float* bih_i  = (const float*)d_in[16];
  const float* bhh_i  = (const float*)d_in[17];
  const float* Wdec   = (const float*)d_in[18];
  const float* bdec   = (const float*)d_in[19];
  const float* g_in   = (const float*)d_in[20];
  const float* b_in   = (const float*)d_in[21];
  const float* Wil    = (const float*)d_in[22];
  const float* bil    = (const float*)d_in[23];
  const float* Wq     = (const float*)d_in[24];
  const float* bq     = (const float*)d_in[25];
  const float* aq     = (const float*)d_in[26];
  const float* gq     = (const float*)d_in[27];
  const float* bgq    = (const float*)d_in[28];
  const float* Wk     = (const float*)d_in[29];
  const float* bk     = (const float*)d_in[30];
  const float* ak     = (const float*)d_in[31];
  const float* gk     = (const float*)d_in[32];
  const float* bgk    = (const float*)d_in[33];
  const float* Wv     = (const float*)d_in[34];
  const float* bv     = (const float*)d_in[35];
  const float* av     = (const float*)d_in[36];
  const float* gv     = (const float*)d_in[37];
  const float* bgv    = (const float*)d_in[38];
  const float* Wp     = (const float*)d_in[39];
  const float* bp     = (const float*)d_in[40];
  const float* ap     = (const float*)d_in[41];
  const float* gp     = (const float*)d_in[42];
  const float* bgp    = (const float*)d_in[43];
  const float* h0     = (const float*)d_in[44];
  const float* c0     = (const float*)d_in[45];
  const float* Kbuf   = (const float*)d_in[46];
  const float* Vbuf   = (const float*)d_in[47];
  float* dout = (float*)d_out;
  float* ws = (float*)d_ws;

  // region aliases (lifetime-disjoint reuse)
  float* zln   = ws + O_R1;             // [16384][128]
  float* Cd    = ws + O_R1;             // [16384][512] (after zln dead)
  float* ys    = ws + O_R1;             // [65536][256] (after Cd dead)
  float* C4    = ws + O_R1;             // [65536][64]  (after ys dead)
  float* C5    = ws + O_R1 + 4194304;   // [65536][128]
  float* Vo    = ws + O_R1;             // [8][512][2048] (after C4/C5 dead)
  float* ygath = ws + O_R1 + 8388608;   // [65536][128]
  float* x1    = ws + O_R2;             // [B,T,QF,C]
  float* Vm    = ws + O_R2;             // (after x1 dead)
  float* y2    = ws + O_R2;             // (after Vm dead)
  float* zcat  = ws + O_R3;             // [16384][512]
  float* z2    = ws + O_R3;             // [128][512][128] (after zcat dead)
  float* C3    = ws + O_R3;             // [65536][128]   (after z2 dead)
  float* Qm    = ws + O_R3;             // [8][512][512]  (after C3 dead)
  float* Km    = ws + O_R3 + 2097152;
  float* attnw = ws + O_ATTN;

  // per-call state init (deterministic under graph replay)
  hipMemsetAsync(ws + O_HF0, 0, 262144 * 4, stream);
  hipMemsetAsync(ws + O_CF,  0, 262144 * 4, stream);
  hipMemsetAsync(ws + O_HB0, 0, 262144 * 4, stream);
  hipMemsetAsync(ws + O_CB,  0, 262144 * 4, stream);
  hipMemcpyAsync(ws + O_HI0, h0, 32768 * 4, hipMemcpyDeviceToDevice, stream);
  hipMemcpyAsync(ws + O_CI,  c0, 32768 * 4, hipMemcpyDeviceToDevice, stream);

  prep_weights<<<546, 256, 0, stream>>>(Wc, bdec, Wil, Wq, Wk, Wv, Wp, ws);

  // ---- intra: conv (stride==kernel) + prelu + LN ----
  gemm64<<<dim3(256, 2), 256, 0, stream>>>(x, ws + O_WCT, zln, 16384, 128, 512, bconv, a_act);
  ln_rows<<<16384, 256, 0, stream>>>(zln, zln, 128, gnorm, bnorm, nullptr, 0);

  // ---- intra bi-LSTM over frequency (16 steps each direction) ----
  for (int t = 0; t < 16; ++t) {
    float* hp = ws + ((t & 1) ? O_HF1 : O_HF0);
    float* hn = ws + ((t & 1) ? O_HF0 : O_HF1);
    lstm_step<<<dim3(64, 16), 256, 0, stream>>>(zln, t, 16, Wih_f, Whh_f, bih_f, bhh_f,
        hp, hn, ws + O_CF, zcat, 16, 512, 0, t);
    float* hpb = ws + ((t & 1) ? O_HB1 : O_HB0);
    float* hnb = ws + ((t & 1) ? O_HB0 : O_HB1);
    lstm_step<<<dim3(64, 16), 256, 0, stream>>>(zln, 15 - t, 16, Wih_b, Whh_b, bih_b, bhh_b,
        hpb, hnb, ws + O_CB, zcat, 16, 512, 256, 15 - t);
  }

  // ---- deconv (stride==kernel transposed conv) + residual ----
  gemm64<<<dim3(256, 8), 256, 0, stream>>>(zcat, Wdec, Cd, 16384, 512, 512, ws + O_BDE, nullptr);
  perm_dec_add<<<32768, 256, 0, stream>>>(Cd, x, x1);

  // ---- inter: LN then causal LSTM over time (512 steps) ----
  ln_rows<<<65536, 256, 0, stream>>>(x1, z2, 128, g_in, b_in, nullptr, 1);
  for (int t = 0; t < 512; ++t) {
    float* hp = ws + ((t & 1) ? O_HI1 : O_HI0);
    float* hn = ws + ((t & 1) ? O_HI0 : O_HI1);
    lstm_step<<<dim3(8, 16), 256, 0, stream>>>(z2, t, 512, Wih_i, Whh_i, bih_i, bhh_i,
        hp, hn, ws + O_CI, ys, 512, 256, 0, t);
  }
  gemm64<<<dim3(1024, 2), 256, 0, stream>>>(ys, ws + O_WILT, C3, 65536, 128, 256, bil, nullptr);
  perm_wil_add<<<32768, 256, 0, stream>>>(C3, x1, dout);  // "out" lives in d_out

  // ---- attention projections ----
  gemm64<<<dim3(1024, 1), 256, 0, stream>>>(dout, ws + O_WQK, C4, 65536, 64, 128, nullptr, nullptr);
  gemm64<<<dim3(1024, 2), 256, 0, stream>>>(dout, ws + O_WVT, C5, 65536, 128, 128, nullptr, nullptr);
  scat_qk<<<16384, 256, 0, stream>>>(C4, bq, bk, aq, ak, Qm, Km);
  scat_v<<<32768, 256, 0, stream>>>(C5, bv, av, Vm);
  ln_rows<<<4096, 256, 0, stream>>>(Qm, Qm, 512, gq, bgq, nullptr, 0);
  ln_rows<<<4096, 256, 0, stream>>>(Km, Km, 512, gk, bgk, nullptr, 0);
  ln_rows<<<4096, 256, 0, stream>>>(Vm, Vm, 2048, gv, bgv, nullptr, 0);

  // ---- banded causal attention ----
  attn_scores<<<dim3(32, 8), 256, 0, stream>>>(Qm, Km, Kbuf, attnw);
  attn_pv<<<dim3(64, 8), 256, 0, stream>>>(attnw, Vm, Vbuf, Vo);

  // ---- output projection + prelu + LN + residual ----
  gather_y<<<32768, 256, 0, stream>>>(Vo, ygath);
  gemm64<<<dim3(1024, 2), 256, 0, stream>>>(ygath, ws + O_WPT, y2, 65536, 128, 128, bp, ap);
  ln_rows<<<1024, 256, 0, stream>>>(y2, dout, 8192, gp, bgp, dout, 0);
}